// Round 1
// baseline (1809.995 us; speedup 1.0000x reference)
//
#include <hip/hip_runtime.h>
#include <hip/hip_bf16.h>

using bf16 = __bf16;
using bf16x8 = __bf16 __attribute__((ext_vector_type(8)));
using f32x4 = float __attribute__((ext_vector_type(4)));

static constexpr long ROWEL = 64L * 768;   // 49152: row stride of [B][N][*] tensors

// ---------------- patchify: x[b,3,128,128] -> flat bf16 [b][n][768] ----------------
__global__ __launch_bounds__(256) void k_patchify(const float* __restrict__ x, bf16* __restrict__ flat)
{
    const int n = blockIdx.x;      // patch 0..63
    const int b = blockIdx.y;      // batch 0..63
    const int i_ = n >> 3, j_ = n & 7;
    for (int it = 0; it < 3; ++it) {
        int f = threadIdx.x + it * 256;
        int c = f >> 8, rem = f & 255, pi = rem >> 4, pj = rem & 15;
        float v = x[(((long)(b * 3 + c)) << 14) + ((i_ * 16 + pi) << 7) + (j_ * 16 + pj)];
        flat[(long)b * ROWEL + n * 768 + f] = (bf16)v;
    }
}

// ---------------- generic bf16-MFMA GEMM, fp32 weights converted during staging ----------------
// C[row][col] = sum_k A[row][k] * B[k][col]  (+bias[col]) (+addm[row][col])
// grid: (Mtiles, Ntiles, Z)   block: 256 (4 waves, 2x2 wave grid)
template<int BM, int BN>
__global__ __launch_bounds__(256) void k_gemm(
    const bf16* __restrict__ A, long lda, long sAz,
    const float* __restrict__ Bw, int ldb, long sBz,
    const float* __restrict__ bias, long sbz,
    const float* __restrict__ addm,
    bf16* __restrict__ Cb, float* __restrict__ Cf, long ldc, long sCz,
    int K)
{
    constexpr int PITCH = 40;               // 32 + 8 pad; 80B row = 16B-aligned, bank-spread
    constexpr int WM = BM / 2, WN = BN / 2;
    constexpr int FM = WM / 16, FN = WN / 16;
    __shared__ bf16 As[BM * PITCH];
    __shared__ bf16 Bs[BN * PITCH];         // stored transposed: [n][k]

    const int tid = threadIdx.x;
    const int lane = tid & 63;
    const int wave = tid >> 6;
    const int wm = wave >> 1, wn = wave & 1;
    const int m0 = blockIdx.x * BM, n0 = blockIdx.y * BN;
    const int z = blockIdx.z;

    const bf16* Az = A + (long)z * sAz;
    const float* Bz = Bw + (long)z * sBz;

    f32x4 acc[FM][FN];
#pragma unroll
    for (int i = 0; i < FM; ++i)
#pragma unroll
        for (int j = 0; j < FN; ++j)
            acc[i][j] = (f32x4){0.f, 0.f, 0.f, 0.f};

    const int nk = K >> 5;
    for (int kt = 0; kt < nk; ++kt) {
        // stage A: BM x 32 bf16 (16B per chunk, 4 chunks per row)
#pragma unroll
        for (int i = 0; i < BM / 64; ++i) {
            int cid = tid + i * 256;
            int r = cid >> 2, seg = cid & 3;
            bf16x8 av = *(const bf16x8*)(Az + (long)(m0 + r) * lda + kt * 32 + seg * 8);
            *(bf16x8*)&As[r * PITCH + seg * 8] = av;
        }
        // stage B: 32 x 128 fp32 -> bf16, transposed into Bs[n][k]  (BN==128)
#pragma unroll
        for (int i = 0; i < 4; ++i) {
            int cid = tid + i * 256;
            int kk = cid >> 5, c4 = (cid & 31) * 4;
            f32x4 bv = *(const f32x4*)(Bz + (long)(kt * 32 + kk) * ldb + n0 + c4);
#pragma unroll
            for (int e = 0; e < 4; ++e)
                Bs[(c4 + e) * PITCH + kk] = (bf16)bv[e];
        }
        __syncthreads();

        bf16x8 af[FM], bfr[FN];
#pragma unroll
        for (int i = 0; i < FM; ++i)
            af[i] = *(const bf16x8*)&As[(wm * WM + i * 16 + (lane & 15)) * PITCH + (lane >> 4) * 8];
#pragma unroll
        for (int j = 0; j < FN; ++j)
            bfr[j] = *(const bf16x8*)&Bs[(wn * WN + j * 16 + (lane & 15)) * PITCH + (lane >> 4) * 8];
#pragma unroll
        for (int i = 0; i < FM; ++i)
#pragma unroll
            for (int j = 0; j < FN; ++j)
                acc[i][j] = __builtin_amdgcn_mfma_f32_16x16x32_bf16(af[i], bfr[j], acc[i][j], 0, 0, 0);
        __syncthreads();
    }

    // epilogue: C layout col=lane&15, row=(lane>>4)*4+reg
#pragma unroll
    for (int j = 0; j < FN; ++j) {
        const int col = n0 + wn * WN + j * 16 + (lane & 15);
        const float bvv = bias ? bias[(long)z * sbz + col] : 0.f;
#pragma unroll
        for (int i = 0; i < FM; ++i) {
#pragma unroll
            for (int r = 0; r < 4; ++r) {
                const long row = m0 + wm * WM + i * 16 + (lane >> 4) * 4 + r;
                const long idx = row * ldc + col + (long)z * sCz;
                float v = acc[i][j][r] + bvv;
                if (addm) v += addm[idx];
                if (Cb) Cb[idx] = (bf16)v;
                if (Cf) Cf[idx] = v;
            }
        }
    }
}

// ---------------- fused attention per patch: S = q k^T/sqrt(768), softmax, P v ----------------
__global__ __launch_bounds__(256) void k_attn(
    const bf16* __restrict__ q, const bf16* __restrict__ k, const bf16* __restrict__ v,
    float* __restrict__ attn)
{
    const int n = blockIdx.x;
    __shared__ bf16 QT[64 * 72];
    __shared__ bf16 KT[64 * 72];
    __shared__ float S[64 * 66];
    __shared__ bf16 P[64 * 72];
    __shared__ bf16 VT[128 * 72];   // v^T chunk: [d][c]

    const int tid = threadIdx.x, lane = tid & 63, wave = tid >> 6;
    const int wm = wave >> 1, wn = wave & 1;

    f32x4 accs[2][2];
#pragma unroll
    for (int i = 0; i < 2; ++i)
#pragma unroll
        for (int j = 0; j < 2; ++j) accs[i][j] = (f32x4){0.f, 0.f, 0.f, 0.f};

    for (int kt = 0; kt < 12; ++kt) {           // K=768, BK=64
#pragma unroll
        for (int i = 0; i < 2; ++i) {
            int cid = tid + i * 256;
            int r = cid >> 3, seg = cid & 7;
            *(bf16x8*)&QT[r * 72 + seg * 8] = *(const bf16x8*)(q + (long)r * ROWEL + n * 768 + kt * 64 + seg * 8);
            *(bf16x8*)&KT[r * 72 + seg * 8] = *(const bf16x8*)(k + (long)r * ROWEL + n * 768 + kt * 64 + seg * 8);
        }
        __syncthreads();
#pragma unroll
        for (int ks = 0; ks < 2; ++ks) {
            bf16x8 qa[2], kb[2];
#pragma unroll
            for (int i = 0; i < 2; ++i)
                qa[i] = *(const bf16x8*)&QT[(wm * 32 + i * 16 + (lane & 15)) * 72 + ks * 32 + (lane >> 4) * 8];
#pragma unroll
            for (int j = 0; j < 2; ++j)
                kb[j] = *(const bf16x8*)&KT[(wn * 32 + j * 16 + (lane & 15)) * 72 + ks * 32 + (lane >> 4) * 8];
#pragma unroll
            for (int i = 0; i < 2; ++i)
#pragma unroll
                for (int j = 0; j < 2; ++j)
                    accs[i][j] = __builtin_amdgcn_mfma_f32_16x16x32_bf16(qa[i], kb[j], accs[i][j], 0, 0, 0);
        }
        __syncthreads();
    }
    const float sc = 0.03608439182435161f;  // 1/sqrt(768)
#pragma unroll
    for (int i = 0; i < 2; ++i)
#pragma unroll
        for (int j = 0; j < 2; ++j)
#pragma unroll
            for (int r = 0; r < 4; ++r)
                S[(wm * 32 + i * 16 + (lane >> 4) * 4 + r) * 66 + wn * 32 + j * 16 + (lane & 15)] = accs[i][j][r] * sc;
    __syncthreads();

    // softmax over c: 4 lanes per row
    {
        int r = tid >> 2, l4 = tid & 3;
        float m = -1e30f;
        for (int c = l4; c < 64; c += 4) m = fmaxf(m, S[r * 66 + c]);
        m = fmaxf(m, __shfl_xor(m, 1));
        m = fmaxf(m, __shfl_xor(m, 2));
        float s = 0.f;
        for (int c = l4; c < 64; c += 4) { float e = __expf(S[r * 66 + c] - m); S[r * 66 + c] = e; s += e; }
        s += __shfl_xor(s, 1);
        s += __shfl_xor(s, 2);
        float inv = 1.f / s;
        for (int c = l4; c < 64; c += 4) P[r * 72 + c] = (bf16)(S[r * 66 + c] * inv);
    }
    __syncthreads();

    // PV: attn[b][n][d] = sum_c P[b][c] v[c][n][d], d in chunks of 128
    for (int dc = 0; dc < 6; ++dc) {
#pragma unroll
        for (int i = 0; i < 4; ++i) {
            int cid = tid + i * 256;
            int c = cid >> 4, seg = cid & 15;
            bf16x8 vv = *(const bf16x8*)(v + (long)c * ROWEL + n * 768 + dc * 128 + seg * 8);
#pragma unroll
            for (int e = 0; e < 8; ++e)
                VT[(seg * 8 + e) * 72 + c] = vv[e];
        }
        __syncthreads();
        f32x4 acco[2][4];
#pragma unroll
        for (int i = 0; i < 2; ++i)
#pragma unroll
            for (int j = 0; j < 4; ++j) acco[i][j] = (f32x4){0.f, 0.f, 0.f, 0.f};
#pragma unroll
        for (int ks = 0; ks < 2; ++ks) {
            bf16x8 pa[2], vb[4];
#pragma unroll
            for (int i = 0; i < 2; ++i)
                pa[i] = *(const bf16x8*)&P[(wm * 32 + i * 16 + (lane & 15)) * 72 + ks * 32 + (lane >> 4) * 8];
#pragma unroll
            for (int j = 0; j < 4; ++j)
                vb[j] = *(const bf16x8*)&VT[(wn * 64 + j * 16 + (lane & 15)) * 72 + ks * 32 + (lane >> 4) * 8];
#pragma unroll
            for (int i = 0; i < 2; ++i)
#pragma unroll
                for (int j = 0; j < 4; ++j)
                    acco[i][j] = __builtin_amdgcn_mfma_f32_16x16x32_bf16(pa[i], vb[j], acco[i][j], 0, 0, 0);
        }
#pragma unroll
        for (int i = 0; i < 2; ++i)
#pragma unroll
            for (int j = 0; j < 4; ++j)
#pragma unroll
                for (int r = 0; r < 4; ++r) {
                    long b = wm * 32 + i * 16 + (lane >> 4) * 4 + r;
                    int d = dc * 128 + wn * 64 + j * 16 + (lane & 15);
                    attn[b * ROWEL + n * 768 + d] = acco[i][j][r];
                }
        __syncthreads();
    }
}

// ---------------- LayerNorm over last dim (768), in place ----------------
__global__ __launch_bounds__(256) void k_ln(float* __restrict__ a,
                                            const float* __restrict__ g, const float* __restrict__ bb)
{
    const long row = blockIdx.x * 4 + (threadIdx.x >> 6);
    const int lane = threadIdx.x & 63;
    float* p = a + row * 768;
    f32x4 xv[3];
    float s = 0.f;
#pragma unroll
    for (int c = 0; c < 3; ++c) {
        xv[c] = *(const f32x4*)(p + c * 256 + lane * 4);
        s += xv[c][0] + xv[c][1] + xv[c][2] + xv[c][3];
    }
#pragma unroll
    for (int o = 1; o < 64; o <<= 1) s += __shfl_xor(s, o);
    const float mu = s * (1.f / 768.f);
    float vs = 0.f;
#pragma unroll
    for (int c = 0; c < 3; ++c)
#pragma unroll
        for (int e = 0; e < 4; ++e) { float d = xv[c][e] - mu; vs += d * d; }
#pragma unroll
    for (int o = 1; o < 64; o <<= 1) vs += __shfl_xor(vs, o);
    const float rstd = rsqrtf(vs * (1.f / 768.f) + 1e-5f);
#pragma unroll
    for (int c = 0; c < 3; ++c)
#pragma unroll
        for (int e = 0; e < 4; ++e) {
            int col = c * 256 + lane * 4 + e;
            p[col] = (xv[c][e] - mu) * rstd * g[col] + bb[col];
        }
}

// ---------------- row softmax over 768, in place ----------------
__global__ __launch_bounds__(256) void k_softmax(float* __restrict__ o)
{
    const long row = blockIdx.x * 4 + (threadIdx.x >> 6);
    const int lane = threadIdx.x & 63;
    float* p = o + row * 768;
    f32x4 xv[3];
    float m = -1e30f;
#pragma unroll
    for (int c = 0; c < 3; ++c) {
        xv[c] = *(const f32x4*)(p + c * 256 + lane * 4);
        m = fmaxf(m, fmaxf(fmaxf(xv[c][0], xv[c][1]), fmaxf(xv[c][2], xv[c][3])));
    }
#pragma unroll
    for (int o2 = 1; o2 < 64; o2 <<= 1) m = fmaxf(m, __shfl_xor(m, o2));
    float s = 0.f;
#pragma unroll
    for (int c = 0; c < 3; ++c)
#pragma unroll
        for (int e = 0; e < 4; ++e) { float ev = __expf(xv[c][e] - m); xv[c][e] = ev; s += ev; }
#pragma unroll
    for (int o2 = 1; o2 < 64; o2 <<= 1) s += __shfl_xor(s, o2);
    const float inv = 1.f / s;
#pragma unroll
    for (int c = 0; c < 3; ++c)
        *(f32x4*)(p + c * 256 + lane * 4) = xv[c] * inv;
}

extern "C" void kernel_launch(void* const* d_in, const int* in_sizes, int n_in,
                              void* d_out, int out_size, void* d_ws, size_t ws_size,
                              hipStream_t stream)
{
    const float* x   = (const float*)d_in[0];
    const float* Wq  = (const float*)d_in[1];
    const float* bq  = (const float*)d_in[2];
    const float* Wk  = (const float*)d_in[3];
    const float* bk  = (const float*)d_in[4];
    const float* Wv  = (const float*)d_in[5];
    const float* bv  = (const float*)d_in[6];
    const float* lng = (const float*)d_in[7];
    const float* lnb = (const float*)d_in[8];
    const float* p1w = (const float*)d_in[9];
    const float* p1b = (const float*)d_in[10];
    const float* w0  = (const float*)d_in[11];
    const float* b0  = (const float*)d_in[12];
    const float* w1  = (const float*)d_in[13];
    const float* b1  = (const float*)d_in[14];
    const float* w2  = (const float*)d_in[15];
    const float* b2  = (const float*)d_in[16];
    const float* w3  = (const float*)d_in[17];
    const float* b3  = (const float*)d_in[18];
    const float* w4  = (const float*)d_in[19];
    const float* b4  = (const float*)d_in[20];
    const float* p2w = (const float*)d_in[21];
    const float* p2b = (const float*)d_in[22];
    float* out = (float*)d_out;

    char* wsbase = (char*)d_ws;
    size_t off = 0;
    auto alloc = [&](size_t bytes) { char* p = wsbase + off; off += (bytes + 255) & ~(size_t)255; return p; };
    bf16*  flat = (bf16*)alloc(4096L * 768 * 2);
    bf16*  qb   = (bf16*)alloc(4096L * 768 * 2);
    bf16*  kb   = (bf16*)alloc(4096L * 768 * 2);
    bf16*  vb2  = (bf16*)alloc(4096L * 768 * 2);
    float* attn = (float*)alloc(4096L * 768 * 4);   // becomes ln in place
    bf16*  att  = (bf16*)alloc(4096L * 768 * 2);
    bf16*  ha   = (bf16*)alloc(4096L * 3072 * 2);
    bf16*  hb   = (bf16*)alloc(4096L * 3072 * 2);
    if (off > ws_size) return;   // fail loudly via poison if ws too small

    k_patchify<<<dim3(64, 64), 256, 0, stream>>>(x, flat);

    // per-patch QKV projections (z = patch)
    k_gemm<64, 128><<<dim3(1, 6, 64), 256, 0, stream>>>(flat, ROWEL, 768, Wq, 768, 589824, bq, 768, nullptr, qb,  nullptr, ROWEL, 768, 768);
    k_gemm<64, 128><<<dim3(1, 6, 64), 256, 0, stream>>>(flat, ROWEL, 768, Wk, 768, 589824, bk, 768, nullptr, kb,  nullptr, ROWEL, 768, 768);
    k_gemm<64, 128><<<dim3(1, 6, 64), 256, 0, stream>>>(flat, ROWEL, 768, Wv, 768, 589824, bv, 768, nullptr, vb2, nullptr, ROWEL, 768, 768);

    k_attn<<<64, 256, 0, stream>>>(qb, kb, vb2, attn);
    k_ln<<<1024, 256, 0, stream>>>(attn, lng, lnb);

    // att = ln + flat @ p1_w + p1_b  -> bf16
    k_gemm<128, 128><<<dim3(32, 6, 1), 256, 0, stream>>>(flat, 768, 0, p1w, 768, 0, p1b, 0, attn, att, nullptr, 768, 0, 768);

    // linear stack
    k_gemm<128, 128><<<dim3(32, 24, 1), 256, 0, stream>>>(att, 768, 0, w0, 3072, 0, b0, 0, nullptr, ha, nullptr, 3072, 0, 768);
    k_gemm<128, 128><<<dim3(32, 24, 1), 256, 0, stream>>>(ha, 3072, 0, w1, 3072, 0, b1, 0, nullptr, hb, nullptr, 3072, 0, 3072);
    k_gemm<128, 128><<<dim3(32, 24, 1), 256, 0, stream>>>(hb, 3072, 0, w2, 3072, 0, b2, 0, nullptr, ha, nullptr, 3072, 0, 3072);
    k_gemm<128, 128><<<dim3(32, 24, 1), 256, 0, stream>>>(ha, 3072, 0, w3, 3072, 0, b3, 0, nullptr, hb, nullptr, 3072, 0, 3072);
    k_gemm<128, 128><<<dim3(32, 6, 1), 256, 0, stream>>>(hb, 3072, 0, w4, 768, 0, b4, 0, nullptr, nullptr, out, 768, 0, 3072);

    // proj = h + att @ p2_w + p2_b (read-modify-write on out, thread-owned locations)
    k_gemm<128, 128><<<dim3(32, 6, 1), 256, 0, stream>>>(att, 768, 0, p2w, 768, 0, p2b, 0, out, nullptr, out, 768, 0, 768);

    k_softmax<<<1024, 256, 0, stream>>>(out);
}

// Round 2
// 817.933 us; speedup vs baseline: 2.2129x; 2.2129x over previous
//
#include <hip/hip_runtime.h>
#include <hip/hip_bf16.h>

using bf16 = __bf16;
using bf16x8 = __bf16 __attribute__((ext_vector_type(8)));
using f32x4 = float __attribute__((ext_vector_type(4)));

static constexpr long ROWEL = 64L * 768;   // row stride of [B][N][*] tensors

// async global->LDS, 16B per lane. lds dest must be wave-uniform base (lane*16 auto).
__device__ __forceinline__ void async16(bf16* lds, const bf16* g)
{
    __builtin_amdgcn_global_load_lds((const __attribute__((address_space(1))) void*)g,
                                     (__attribute__((address_space(3))) void*)lds, 16, 0, 0);
}

// ---------------- patchify: x[b,3,128,128] -> flat bf16 [b][n][768] ----------------
__global__ __launch_bounds__(256) void k_patchify(const float* __restrict__ x, bf16* __restrict__ flat)
{
    const int n = blockIdx.x;      // patch 0..63
    const int b = blockIdx.y;      // batch 0..63
    const int i_ = n >> 3, j_ = n & 7;
    for (int it = 0; it < 3; ++it) {
        int f = threadIdx.x + it * 256;
        int c = f >> 8, rem = f & 255, pi = rem >> 4, pj = rem & 15;
        float v = x[(((long)(b * 3 + c)) << 14) + ((i_ * 16 + pi) << 7) + (j_ * 16 + pj)];
        flat[(long)b * ROWEL + n * 768 + f] = (bf16)v;
    }
}

// ---------------- weight convert+transpose: W fp32 [K][N] -> Wt bf16 [N][K] ----------------
__global__ __launch_bounds__(256) void k_cvt_t(const float* __restrict__ W, bf16* __restrict__ Wt,
                                               int Kd, int Nd)
{
    __shared__ bf16 T[64 * 66];
    const int k0 = blockIdx.x * 64, n0 = blockIdx.y * 64;
    const int tid = threadIdx.x;
    const int kr = tid >> 4, nc = (tid & 15) * 4;
#pragma unroll
    for (int i = 0; i < 4; ++i) {
        f32x4 v = *(const f32x4*)(W + (long)(k0 + kr + i * 16) * Nd + n0 + nc);
#pragma unroll
        for (int e = 0; e < 4; ++e)
            T[(kr + i * 16) * 66 + nc + e] = (bf16)v[e];
    }
    __syncthreads();
    const int nr = tid >> 3, ks = (tid & 7) * 8;
#pragma unroll
    for (int it = 0; it < 2; ++it) {
        int n = nr + it * 32;
        bf16x8 o;
#pragma unroll
        for (int j = 0; j < 8; ++j) o[j] = T[(ks + j) * 66 + n];
        *(bf16x8*)(Wt + (long)(n0 + n) * Kd + k0 + ks) = o;
    }
}

// ---------------- m97-style GEMM: A bf16 [M][lda], Bt bf16 [N][K], C = A*B (+bias)(+addm) ----------------
// 128x128 tile, BK=32, 4 waves (2x2), global_load_lds staging, linear LDS.
__global__ __launch_bounds__(256) void k_gemm_bt(
    const bf16* __restrict__ A, long lda,
    const bf16* __restrict__ Bt, int K,
    const float* __restrict__ bias,
    const float* __restrict__ addm,
    bf16* __restrict__ Cb, float* __restrict__ Cf, long ldc)
{
    __shared__ bf16 As[128 * 32];
    __shared__ bf16 Bs[128 * 32];
    const int tid = threadIdx.x, lane = tid & 63, wave = tid >> 6;
    const int wm = wave >> 1, wn = wave & 1;
    const long m0 = (long)blockIdx.x * 128, n0 = (long)blockIdx.y * 128;

    f32x4 acc[4][4];
#pragma unroll
    for (int i = 0; i < 4; ++i)
#pragma unroll
        for (int j = 0; j < 4; ++j) acc[i][j] = (f32x4){0.f, 0.f, 0.f, 0.f};

    const int nk = K >> 5;
    for (int kt = 0; kt < nk; ++kt) {
        const long kb = (long)kt * 32;
#pragma unroll
        for (int i = 0; i < 2; ++i) {
            const int idx = tid + i * 256;
            const int r = idx >> 2, seg = idx & 3;
            async16(&As[(i * 256 + wave * 64) * 8], A + (m0 + r) * lda + kb + seg * 8);
            async16(&Bs[(i * 256 + wave * 64) * 8], Bt + (n0 + r) * (long)K + kb + seg * 8);
        }
        __syncthreads();
        bf16x8 af[4], bfr[4];
#pragma unroll
        for (int i = 0; i < 4; ++i)
            af[i] = *(const bf16x8*)&As[(wm * 64 + i * 16 + (lane & 15)) * 32 + (lane >> 4) * 8];
#pragma unroll
        for (int j = 0; j < 4; ++j)
            bfr[j] = *(const bf16x8*)&Bs[(wn * 64 + j * 16 + (lane & 15)) * 32 + (lane >> 4) * 8];
#pragma unroll
        for (int i = 0; i < 4; ++i)
#pragma unroll
            for (int j = 0; j < 4; ++j)
                acc[i][j] = __builtin_amdgcn_mfma_f32_16x16x32_bf16(af[i], bfr[j], acc[i][j], 0, 0, 0);
        __syncthreads();
    }

#pragma unroll
    for (int j = 0; j < 4; ++j) {
        const long col = n0 + wn * 64 + j * 16 + (lane & 15);
        const float bb = bias ? bias[col] : 0.f;
#pragma unroll
        for (int i = 0; i < 4; ++i) {
#pragma unroll
            for (int r = 0; r < 4; ++r) {
                const long row = m0 + wm * 64 + i * 16 + (lane >> 4) * 4 + r;
                const long idx = row * ldc + col;
                float v = acc[i][j][r] + bb;
                if (addm) v += addm[idx];
                if (Cb) Cb[idx] = (bf16)v;
                if (Cf) Cf[idx] = v;
            }
        }
    }
}

// ---------------- legacy GEMM (fp32 B, in-kernel cvt) — used for QKV only this round ----------------
template<int BM, int BN>
__global__ __launch_bounds__(256) void k_gemm(
    const bf16* __restrict__ A, long lda, long sAz,
    const float* __restrict__ Bw, int ldb, long sBz,
    const float* __restrict__ bias, long sbz,
    const float* __restrict__ addm,
    bf16* __restrict__ Cb, float* __restrict__ Cf, long ldc, long sCz,
    int K)
{
    constexpr int PITCH = 40;
    constexpr int WM = BM / 2, WN = BN / 2;
    constexpr int FM = WM / 16, FN = WN / 16;
    __shared__ bf16 As[BM * PITCH];
    __shared__ bf16 Bs[BN * PITCH];

    const int tid = threadIdx.x;
    const int lane = tid & 63;
    const int wave = tid >> 6;
    const int wm = wave >> 1, wn = wave & 1;
    const int m0 = blockIdx.x * BM, n0 = blockIdx.y * BN;
    const int z = blockIdx.z;

    const bf16* Az = A + (long)z * sAz;
    const float* Bz = Bw + (long)z * sBz;

    f32x4 acc[FM][FN];
#pragma unroll
    for (int i = 0; i < FM; ++i)
#pragma unroll
        for (int j = 0; j < FN; ++j)
            acc[i][j] = (f32x4){0.f, 0.f, 0.f, 0.f};

    const int nk = K >> 5;
    for (int kt = 0; kt < nk; ++kt) {
#pragma unroll
        for (int i = 0; i < BM / 64; ++i) {
            int cid = tid + i * 256;
            int r = cid >> 2, seg = cid & 3;
            bf16x8 av = *(const bf16x8*)(Az + (long)(m0 + r) * lda + kt * 32 + seg * 8);
            *(bf16x8*)&As[r * PITCH + seg * 8] = av;
        }
#pragma unroll
        for (int i = 0; i < 4; ++i) {
            int cid = tid + i * 256;
            int kk = cid >> 5, c4 = (cid & 31) * 4;
            f32x4 bv = *(const f32x4*)(Bz + (long)(kt * 32 + kk) * ldb + n0 + c4);
#pragma unroll
            for (int e = 0; e < 4; ++e)
                Bs[(c4 + e) * PITCH + kk] = (bf16)bv[e];
        }
        __syncthreads();

        bf16x8 af[FM], bfr[FN];
#pragma unroll
        for (int i = 0; i < FM; ++i)
            af[i] = *(const bf16x8*)&As[(wm * WM + i * 16 + (lane & 15)) * PITCH + (lane >> 4) * 8];
#pragma unroll
        for (int j = 0; j < FN; ++j)
            bfr[j] = *(const bf16x8*)&Bs[(wn * WN + j * 16 + (lane & 15)) * PITCH + (lane >> 4) * 8];
#pragma unroll
        for (int i = 0; i < FM; ++i)
#pragma unroll
            for (int j = 0; j < FN; ++j)
                acc[i][j] = __builtin_amdgcn_mfma_f32_16x16x32_bf16(af[i], bfr[j], acc[i][j], 0, 0, 0);
        __syncthreads();
    }

#pragma unroll
    for (int j = 0; j < FN; ++j) {
        const int col = n0 + wn * WN + j * 16 + (lane & 15);
        const float bvv = bias ? bias[(long)z * sbz + col] : 0.f;
#pragma unroll
        for (int i = 0; i < FM; ++i) {
#pragma unroll
            for (int r = 0; r < 4; ++r) {
                const long row = m0 + wm * WM + i * 16 + (lane >> 4) * 4 + r;
                const long idx = row * ldc + col + (long)z * sCz;
                float v = acc[i][j][r] + bvv;
                if (addm) v += addm[idx];
                if (Cb) Cb[idx] = (bf16)v;
                if (Cf) Cf[idx] = v;
            }
        }
    }
}

// ---------------- fused attention per patch ----------------
__global__ __launch_bounds__(256) void k_attn(
    const bf16* __restrict__ q, const bf16* __restrict__ k, const bf16* __restrict__ v,
    float* __restrict__ attn)
{
    const int n = blockIdx.x;
    __shared__ bf16 QT[64 * 72];
    __shared__ bf16 KT[64 * 72];
    __shared__ float S[64 * 66];
    __shared__ bf16 P[64 * 72];
    __shared__ bf16 VT[128 * 72];

    const int tid = threadIdx.x, lane = tid & 63, wave = tid >> 6;
    const int wm = wave >> 1, wn = wave & 1;

    f32x4 accs[2][2];
#pragma unroll
    for (int i = 0; i < 2; ++i)
#pragma unroll
        for (int j = 0; j < 2; ++j) accs[i][j] = (f32x4){0.f, 0.f, 0.f, 0.f};

    for (int kt = 0; kt < 12; ++kt) {
#pragma unroll
        for (int i = 0; i < 2; ++i) {
            int cid = tid + i * 256;
            int r = cid >> 3, seg = cid & 7;
            *(bf16x8*)&QT[r * 72 + seg * 8] = *(const bf16x8*)(q + (long)r * ROWEL + n * 768 + kt * 64 + seg * 8);
            *(bf16x8*)&KT[r * 72 + seg * 8] = *(const bf16x8*)(k + (long)r * ROWEL + n * 768 + kt * 64 + seg * 8);
        }
        __syncthreads();
#pragma unroll
        for (int ks = 0; ks < 2; ++ks) {
            bf16x8 qa[2], kb[2];
#pragma unroll
            for (int i = 0; i < 2; ++i)
                qa[i] = *(const bf16x8*)&QT[(wm * 32 + i * 16 + (lane & 15)) * 72 + ks * 32 + (lane >> 4) * 8];
#pragma unroll
            for (int j = 0; j < 2; ++j)
                kb[j] = *(const bf16x8*)&KT[(wn * 32 + j * 16 + (lane & 15)) * 72 + ks * 32 + (lane >> 4) * 8];
#pragma unroll
            for (int i = 0; i < 2; ++i)
#pragma unroll
                for (int j = 0; j < 2; ++j)
                    accs[i][j] = __builtin_amdgcn_mfma_f32_16x16x32_bf16(qa[i], kb[j], accs[i][j], 0, 0, 0);
        }
        __syncthreads();
    }
    const float sc = 0.03608439182435161f;
#pragma unroll
    for (int i = 0; i < 2; ++i)
#pragma unroll
        for (int j = 0; j < 2; ++j)
#pragma unroll
            for (int r = 0; r < 4; ++r)
                S[(wm * 32 + i * 16 + (lane >> 4) * 4 + r) * 66 + wn * 32 + j * 16 + (lane & 15)] = accs[i][j][r] * sc;
    __syncthreads();

    {
        int r = tid >> 2, l4 = tid & 3;
        float m = -1e30f;
        for (int c = l4; c < 64; c += 4) m = fmaxf(m, S[r * 66 + c]);
        m = fmaxf(m, __shfl_xor(m, 1));
        m = fmaxf(m, __shfl_xor(m, 2));
        float s = 0.f;
        for (int c = l4; c < 64; c += 4) { float e = __expf(S[r * 66 + c] - m); S[r * 66 + c] = e; s += e; }
        s += __shfl_xor(s, 1);
        s += __shfl_xor(s, 2);
        float inv = 1.f / s;
        for (int c = l4; c < 64; c += 4) P[r * 72 + c] = (bf16)(S[r * 66 + c] * inv);
    }
    __syncthreads();

    for (int dc = 0; dc < 6; ++dc) {
#pragma unroll
        for (int i = 0; i < 4; ++i) {
            int cid = tid + i * 256;
            int c = cid >> 4, seg = cid & 15;
            bf16x8 vv = *(const bf16x8*)(v + (long)c * ROWEL + n * 768 + dc * 128 + seg * 8);
#pragma unroll
            for (int e = 0; e < 8; ++e)
                VT[(seg * 8 + e) * 72 + c] = vv[e];
        }
        __syncthreads();
        f32x4 acco[2][4];
#pragma unroll
        for (int i = 0; i < 2; ++i)
#pragma unroll
            for (int j = 0; j < 4; ++j) acco[i][j] = (f32x4){0.f, 0.f, 0.f, 0.f};
#pragma unroll
        for (int ks = 0; ks < 2; ++ks) {
            bf16x8 pa[2], vb[4];
#pragma unroll
            for (int i = 0; i < 2; ++i)
                pa[i] = *(const bf16x8*)&P[(wm * 32 + i * 16 + (lane & 15)) * 72 + ks * 32 + (lane >> 4) * 8];
#pragma unroll
            for (int j = 0; j < 4; ++j)
                vb[j] = *(const bf16x8*)&VT[(wn * 64 + j * 16 + (lane & 15)) * 72 + ks * 32 + (lane >> 4) * 8];
#pragma unroll
            for (int i = 0; i < 2; ++i)
#pragma unroll
                for (int j = 0; j < 4; ++j)
                    acco[i][j] = __builtin_amdgcn_mfma_f32_16x16x32_bf16(pa[i], vb[j], acco[i][j], 0, 0, 0);
        }
#pragma unroll
        for (int i = 0; i < 2; ++i)
#pragma unroll
            for (int j = 0; j < 4; ++j)
#pragma unroll
                for (int r = 0; r < 4; ++r) {
                    long b = wm * 32 + i * 16 + (lane >> 4) * 4 + r;
                    int d = dc * 128 + wn * 64 + j * 16 + (lane & 15);
                    attn[b * ROWEL + n * 768 + d] = acco[i][j][r];
                }
        __syncthreads();
    }
}

// ---------------- LayerNorm over last dim (768), in place ----------------
__global__ __launch_bounds__(256) void k_ln(float* __restrict__ a,
                                            const float* __restrict__ g, const float* __restrict__ bb)
{
    const long row = blockIdx.x * 4 + (threadIdx.x >> 6);
    const int lane = threadIdx.x & 63;
    float* p = a + row * 768;
    f32x4 xv[3];
    float s = 0.f;
#pragma unroll
    for (int c = 0; c < 3; ++c) {
        xv[c] = *(const f32x4*)(p + c * 256 + lane * 4);
        s += xv[c][0] + xv[c][1] + xv[c][2] + xv[c][3];
    }
#pragma unroll
    for (int o = 1; o < 64; o <<= 1) s += __shfl_xor(s, o);
    const float mu = s * (1.f / 768.f);
    float vs = 0.f;
#pragma unroll
    for (int c = 0; c < 3; ++c)
#pragma unroll
        for (int e = 0; e < 4; ++e) { float d = xv[c][e] - mu; vs += d * d; }
#pragma unroll
    for (int o = 1; o < 64; o <<= 1) vs += __shfl_xor(vs, o);
    const float rstd = rsqrtf(vs * (1.f / 768.f) + 1e-5f);
#pragma unroll
    for (int c = 0; c < 3; ++c)
#pragma unroll
        for (int e = 0; e < 4; ++e) {
            int col = c * 256 + lane * 4 + e;
            p[col] = (xv[c][e] - mu) * rstd * g[col] + bb[col];
        }
}

// ---------------- row softmax over 768, in place ----------------
__global__ __launch_bounds__(256) void k_softmax(float* __restrict__ o)
{
    const long row = blockIdx.x * 4 + (threadIdx.x >> 6);
    const int lane = threadIdx.x & 63;
    float* p = o + row * 768;
    f32x4 xv[3];
    float m = -1e30f;
#pragma unroll
    for (int c = 0; c < 3; ++c) {
        xv[c] = *(const f32x4*)(p + c * 256 + lane * 4);
        m = fmaxf(m, fmaxf(fmaxf(xv[c][0], xv[c][1]), fmaxf(xv[c][2], xv[c][3])));
    }
#pragma unroll
    for (int o2 = 1; o2 < 64; o2 <<= 1) m = fmaxf(m, __shfl_xor(m, o2));
    float s = 0.f;
#pragma unroll
    for (int c = 0; c < 3; ++c)
#pragma unroll
        for (int e = 0; e < 4; ++e) { float ev = __expf(xv[c][e] - m); xv[c][e] = ev; s += ev; }
#pragma unroll
    for (int o2 = 1; o2 < 64; o2 <<= 1) s += __shfl_xor(s, o2);
    const float inv = 1.f / s;
#pragma unroll
    for (int c = 0; c < 3; ++c)
        *(f32x4*)(p + c * 256 + lane * 4) = xv[c] * inv;
}

extern "C" void kernel_launch(void* const* d_in, const int* in_sizes, int n_in,
                              void* d_out, int out_size, void* d_ws, size_t ws_size,
                              hipStream_t stream)
{
    const float* x   = (const float*)d_in[0];
    const float* Wq  = (const float*)d_in[1];
    const float* bq  = (const float*)d_in[2];
    const float* Wk  = (const float*)d_in[3];
    const float* bk  = (const float*)d_in[4];
    const float* Wv  = (const float*)d_in[5];
    const float* bv  = (const float*)d_in[6];
    const float* lng = (const float*)d_in[7];
    const float* lnb = (const float*)d_in[8];
    const float* p1w = (const float*)d_in[9];
    const float* p1b = (const float*)d_in[10];
    const float* w0  = (const float*)d_in[11];
    const float* b0  = (const float*)d_in[12];
    const float* w1  = (const float*)d_in[13];
    const float* b1  = (const float*)d_in[14];
    const float* w2  = (const float*)d_in[15];
    const float* b2  = (const float*)d_in[16];
    const float* w3  = (const float*)d_in[17];
    const float* b3  = (const float*)d_in[18];
    const float* w4  = (const float*)d_in[19];
    const float* b4  = (const float*)d_in[20];
    const float* p2w = (const float*)d_in[21];
    const float* p2b = (const float*)d_in[22];
    float* out = (float*)d_out;

    char* wsbase = (char*)d_ws;
    size_t off = 0;
    auto alloc = [&](size_t bytes) { char* p = wsbase + off; off += (bytes + 255) & ~(size_t)255; return p; };
    bf16*  flat = (bf16*)alloc(4096L * 768 * 2);
    bf16*  qb   = (bf16*)alloc(4096L * 768 * 2);
    bf16*  kb   = (bf16*)alloc(4096L * 768 * 2);
    bf16*  vb2  = (bf16*)alloc(4096L * 768 * 2);
    float* attn = (float*)alloc(4096L * 768 * 4);
    bf16*  att  = (bf16*)alloc(4096L * 768 * 2);
    bf16*  ha   = (bf16*)alloc(4096L * 3072 * 2);
    bf16*  hb   = (bf16*)alloc(4096L * 3072 * 2);
    // transposed bf16 weights [N][K]
    bf16*  p1t  = (bf16*)alloc(768L * 768 * 2);
    bf16*  w0t  = (bf16*)alloc(3072L * 768 * 2);
    bf16*  w1t  = (bf16*)alloc(3072L * 3072 * 2);
    bf16*  w2t  = (bf16*)alloc(3072L * 3072 * 2);
    bf16*  w3t  = (bf16*)alloc(3072L * 3072 * 2);
    bf16*  w4t  = (bf16*)alloc(768L * 3072 * 2);
    bf16*  p2t  = (bf16*)alloc(768L * 768 * 2);
    if (off > ws_size) return;

    // weight pre-pass (independent of activations)
    k_cvt_t<<<dim3(12, 12), 256, 0, stream>>>(p1w, p1t, 768, 768);
    k_cvt_t<<<dim3(12, 48), 256, 0, stream>>>(w0,  w0t, 768, 3072);
    k_cvt_t<<<dim3(48, 48), 256, 0, stream>>>(w1,  w1t, 3072, 3072);
    k_cvt_t<<<dim3(48, 48), 256, 0, stream>>>(w2,  w2t, 3072, 3072);
    k_cvt_t<<<dim3(48, 48), 256, 0, stream>>>(w3,  w3t, 3072, 3072);
    k_cvt_t<<<dim3(48, 12), 256, 0, stream>>>(w4,  w4t, 3072, 768);
    k_cvt_t<<<dim3(12, 12), 256, 0, stream>>>(p2w, p2t, 768, 768);

    k_patchify<<<dim3(64, 64), 256, 0, stream>>>(x, flat);

    // per-patch QKV projections (legacy path; fp32 weights read once)
    k_gemm<64, 128><<<dim3(1, 6, 64), 256, 0, stream>>>(flat, ROWEL, 768, Wq, 768, 589824, bq, 768, nullptr, qb,  nullptr, ROWEL, 768, 768);
    k_gemm<64, 128><<<dim3(1, 6, 64), 256, 0, stream>>>(flat, ROWEL, 768, Wk, 768, 589824, bk, 768, nullptr, kb,  nullptr, ROWEL, 768, 768);
    k_gemm<64, 128><<<dim3(1, 6, 64), 256, 0, stream>>>(flat, ROWEL, 768, Wv, 768, 589824, bv, 768, nullptr, vb2, nullptr, ROWEL, 768, 768);

    k_attn<<<64, 256, 0, stream>>>(qb, kb, vb2, attn);
    k_ln<<<1024, 256, 0, stream>>>(attn, lng, lnb);

    // att = ln + flat @ p1_w + p1_b  -> bf16
    k_gemm_bt<<<dim3(32, 6), 256, 0, stream>>>(flat, 768, p1t, 768, p1b, attn, att, nullptr, 768);

    // linear stack
    k_gemm_bt<<<dim3(32, 24), 256, 0, stream>>>(att, 768,  w0t, 768,  b0, nullptr, ha, nullptr, 3072);
    k_gemm_bt<<<dim3(32, 24), 256, 0, stream>>>(ha, 3072,  w1t, 3072, b1, nullptr, hb, nullptr, 3072);
    k_gemm_bt<<<dim3(32, 24), 256, 0, stream>>>(hb, 3072,  w2t, 3072, b2, nullptr, ha, nullptr, 3072);
    k_gemm_bt<<<dim3(32, 24), 256, 0, stream>>>(ha, 3072,  w3t, 3072, b3, nullptr, hb, nullptr, 3072);
    k_gemm_bt<<<dim3(32, 6),  256, 0, stream>>>(hb, 3072,  w4t, 3072, b4, nullptr, nullptr, out, 768);

    // proj = h + att @ p2_w + p2_b
    k_gemm_bt<<<dim3(32, 6),  256, 0, stream>>>(att, 768,  p2t, 768,  p2b, out, nullptr, out, 768);

    k_softmax<<<1024, 256, 0, stream>>>(out);
}

// Round 3
// 509.894 us; speedup vs baseline: 3.5497x; 1.6041x over previous
//
#include <hip/hip_runtime.h>
#include <hip/hip_bf16.h>

using bf16 = __bf16;
using bf16x8 = __bf16 __attribute__((ext_vector_type(8)));
using f32x4 = float __attribute__((ext_vector_type(4)));

static constexpr long ROWEL = 64L * 768;   // row stride of [B][N][*] tensors

// async global->LDS, 16B per lane. lds dest wave-uniform base; lane offset = lane*16B.
__device__ __forceinline__ void async16(void* lds, const void* g)
{
    __builtin_amdgcn_global_load_lds((const __attribute__((address_space(1))) void*)g,
                                     (__attribute__((address_space(3))) void*)lds, 16, 0, 0);
}

// ---------------- patchify: x[b,3,128,128] -> flat bf16 [b][n][768] ----------------
__global__ __launch_bounds__(256) void k_patchify(const float* __restrict__ x, bf16* __restrict__ flat)
{
    const int n = blockIdx.x;      // patch 0..63
    const int b = blockIdx.y;      // batch 0..63
    const int i_ = n >> 3, j_ = n & 7;
    for (int it = 0; it < 3; ++it) {
        int f = threadIdx.x + it * 256;
        int c = f >> 8, rem = f & 255, pi = rem >> 4, pj = rem & 15;
        float v = x[(((long)(b * 3 + c)) << 14) + ((i_ * 16 + pi) << 7) + (j_ * 16 + pj)];
        flat[(long)b * ROWEL + n * 768 + f] = (bf16)v;
    }
}

// ---------------- weight convert+transpose: W fp32 [K][N] -> Wt bf16 [N][K] ----------------
__global__ __launch_bounds__(256) void k_cvt_t(const float* __restrict__ W, bf16* __restrict__ Wt,
                                               int Kd, int Nd)
{
    __shared__ bf16 T[64 * 66];
    const int k0 = blockIdx.x * 64, n0 = blockIdx.y * 64;
    const int tid = threadIdx.x;
    const int kr = tid >> 4, nc = (tid & 15) * 4;
#pragma unroll
    for (int i = 0; i < 4; ++i) {
        f32x4 v = *(const f32x4*)(W + (long)(k0 + kr + i * 16) * Nd + n0 + nc);
#pragma unroll
        for (int e = 0; e < 4; ++e)
            T[(kr + i * 16) * 66 + nc + e] = (bf16)v[e];
    }
    __syncthreads();
    const int nr = tid >> 3, ks = (tid & 7) * 8;
#pragma unroll
    for (int it = 0; it < 2; ++it) {
        int n = nr + it * 32;
        bf16x8 o;
#pragma unroll
        for (int j = 0; j < 8; ++j) o[j] = T[(ks + j) * 66 + n];
        *(bf16x8*)(Wt + (long)(n0 + n) * Kd + k0 + ks) = o;
    }
}

// ---------------- plain fp32 -> bf16 cast ----------------
__global__ __launch_bounds__(256) void k_cast(const float* __restrict__ W, bf16* __restrict__ o, long nelem)
{
    long i = ((long)blockIdx.x * 256 + threadIdx.x) * 8;
    if (i >= nelem) return;
    f32x4 a = *(const f32x4*)(W + i);
    f32x4 b = *(const f32x4*)(W + i + 4);
    bf16x8 v;
#pragma unroll
    for (int e = 0; e < 4; ++e) { v[e] = (bf16)a[e]; v[4 + e] = (bf16)b[e]; }
    *(bf16x8*)(o + i) = v;
}

// ---------------- m97-style GEMM: A bf16 [M][lda], Bt bf16 [N][ldb], C = A*B (+bias)(+addm) ----------------
template<int BM, int BN>
__global__ __launch_bounds__(256) void k_gemm_bt(
    const bf16* __restrict__ A, long lda,
    const bf16* __restrict__ Bt, long ldb,
    int K,
    const float* __restrict__ bias,
    const float* __restrict__ addm,
    bf16* __restrict__ Cb, float* __restrict__ Cf, long ldc)
{
    constexpr int WM = BM / 2, WN = BN / 2, FM = WM / 16, FN = WN / 16;
    __shared__ bf16 As[BM * 32];
    __shared__ bf16 Bs[BN * 32];
    const int tid = threadIdx.x, lane = tid & 63, wave = tid >> 6;
    const int wm = wave >> 1, wn = wave & 1;
    const long m0 = (long)blockIdx.x * BM, n0 = (long)blockIdx.y * BN;

    f32x4 acc[FM][FN];
#pragma unroll
    for (int i = 0; i < FM; ++i)
#pragma unroll
        for (int j = 0; j < FN; ++j) acc[i][j] = (f32x4){0.f, 0.f, 0.f, 0.f};

    const int nk = K >> 5;
    for (int kt = 0; kt < nk; ++kt) {
        const long kb = (long)kt * 32;
#pragma unroll
        for (int i = 0; i < BM / 64; ++i) {
            const int idx = tid + i * 256;
            const int r = idx >> 2, seg = idx & 3;
            async16(&As[(i * 256 + wave * 64) * 8], A + (m0 + r) * lda + kb + seg * 8);
        }
#pragma unroll
        for (int i = 0; i < BN / 64; ++i) {
            const int idx = tid + i * 256;
            const int r = idx >> 2, seg = idx & 3;
            async16(&Bs[(i * 256 + wave * 64) * 8], Bt + (n0 + r) * ldb + kb + seg * 8);
        }
        __syncthreads();
        bf16x8 af[FM], bfr[FN];
#pragma unroll
        for (int i = 0; i < FM; ++i)
            af[i] = *(const bf16x8*)&As[(wm * WM + i * 16 + (lane & 15)) * 32 + (lane >> 4) * 8];
#pragma unroll
        for (int j = 0; j < FN; ++j)
            bfr[j] = *(const bf16x8*)&Bs[(wn * WN + j * 16 + (lane & 15)) * 32 + (lane >> 4) * 8];
#pragma unroll
        for (int i = 0; i < FM; ++i)
#pragma unroll
            for (int j = 0; j < FN; ++j)
                acc[i][j] = __builtin_amdgcn_mfma_f32_16x16x32_bf16(af[i], bfr[j], acc[i][j], 0, 0, 0);
        __syncthreads();
    }

#pragma unroll
    for (int j = 0; j < FN; ++j) {
        const long col = n0 + wn * WN + j * 16 + (lane & 15);
        const float bb = bias ? bias[col] : 0.f;
#pragma unroll
        for (int i = 0; i < FM; ++i) {
#pragma unroll
            for (int r = 0; r < 4; ++r) {
                const long row = m0 + wm * WM + i * 16 + (lane >> 4) * 4 + r;
                const long idx = row * ldc + col;
                float v = acc[i][j][r] + bb;
                if (addm) v += addm[idx];
                if (Cb) Cb[idx] = (bf16)v;
                if (Cf) Cf[idx] = v;
            }
        }
    }
}

// ---------------- QKV: per-patch GEMM, fp32 weights DMA'd to LDS, cvt at fragment read ----------------
// grid (12, 64): (n-tile of 64, patch). out[b][z][n] = sum_k flat[b][z*768+k] * W[z][k][n] + bias[z][n]
__global__ __launch_bounds__(256) void k_qkv(
    const bf16* __restrict__ flat, const float* __restrict__ W, const float* __restrict__ bias,
    bf16* __restrict__ out)
{
    __shared__ bf16 As[64 * 32];     // [b][k] bf16
    __shared__ float Bs[32 * 64];    // [k][n] fp32
    const int tid = threadIdx.x, lane = tid & 63, wave = tid >> 6;
    const int wm = wave >> 1, wn = wave & 1;
    const int n0 = blockIdx.x * 64;
    const int z = blockIdx.y;
    const float* Wz = W + (long)z * 589824;

    f32x4 acc[2][2];
#pragma unroll
    for (int i = 0; i < 2; ++i)
#pragma unroll
        for (int j = 0; j < 2; ++j) acc[i][j] = (f32x4){0.f, 0.f, 0.f, 0.f};

    for (int kt = 0; kt < 24; ++kt) {
        const int kb = kt * 32;
        // A: 64x32 bf16 = 4KB, 1 issue
        {
            const int r = tid >> 2, seg = tid & 3;
            async16(&As[wave * 512], flat + (long)r * ROWEL + z * 768 + kb + seg * 8);
        }
        // B: 32x64 fp32 = 8KB linear [k][n], 2 issues; each wave-issue covers 4 k-rows
#pragma unroll
        for (int i = 0; i < 2; ++i) {
            const int g = i * 4 + wave;                 // row-group 0..7
            const int kk = kb + g * 4 + (lane >> 4);    // global k
            const int nn = (lane & 15) * 4;
            async16(&Bs[g * 256], Wz + (long)kk * 768 + n0 + nn);
        }
        __syncthreads();
        bf16x8 af[2], bfr[2];
#pragma unroll
        for (int i = 0; i < 2; ++i)
            af[i] = *(const bf16x8*)&As[(wm * 32 + i * 16 + (lane & 15)) * 32 + (lane >> 4) * 8];
#pragma unroll
        for (int j = 0; j < 2; ++j) {
            const int n = wn * 32 + j * 16 + (lane & 15);
            const int kf = (lane >> 4) * 8;
            bf16x8 b;
#pragma unroll
            for (int e = 0; e < 8; ++e) b[e] = (bf16)Bs[(kf + e) * 64 + n];
            bfr[j] = b;
        }
#pragma unroll
        for (int i = 0; i < 2; ++i)
#pragma unroll
            for (int j = 0; j < 2; ++j)
                acc[i][j] = __builtin_amdgcn_mfma_f32_16x16x32_bf16(af[i], bfr[j], acc[i][j], 0, 0, 0);
        __syncthreads();
    }

#pragma unroll
    for (int j = 0; j < 2; ++j) {
        const int col = n0 + wn * 32 + j * 16 + (lane & 15);
        const float bb = bias[z * 768 + col];
#pragma unroll
        for (int i = 0; i < 2; ++i) {
#pragma unroll
            for (int r = 0; r < 4; ++r) {
                const int row = wm * 32 + i * 16 + (lane >> 4) * 4 + r;   // batch index
                out[(long)row * ROWEL + z * 768 + col] = (bf16)(acc[i][j][r] + bb);
            }
        }
    }
}

// ---------------- bias chain: outP[kc][n] = sum_{k in chunk kc} vin[k] * W[k][n] ----------------
// grid (N/64, 8), block 256 (4 k-quarters of 64 threads)
__global__ __launch_bounds__(256) void k_vm(
    const float* __restrict__ vin, const float* __restrict__ W,
    int K, int N, float* __restrict__ outP)
{
    __shared__ float red[4][64];
    const int tid = threadIdx.x;
    const int nl = tid & 63, kq = tid >> 6;
    const int n = blockIdx.x * 64 + nl;
    const int kc = blockIdx.y;
    const int kchunk = K / 8, kslice = kchunk / 4;
    const int k0 = kc * kchunk + kq * kslice;
    float acc = 0.f;
#pragma unroll 8
    for (int k = k0; k < k0 + kslice; ++k)
        acc += vin[k] * W[(long)k * N + n];
    red[kq][nl] = acc;
    __syncthreads();
    if (kq == 0)
        outP[(long)kc * N + n] = red[0][nl] + red[1][nl] + red[2][nl] + red[3][nl];
}

__global__ __launch_bounds__(256) void k_vred(
    const float* __restrict__ P, const float* __restrict__ b1, const float* __restrict__ b2,
    int N, float* __restrict__ out)
{
    const int n = blockIdx.x * 256 + threadIdx.x;
    if (n >= N) return;
    float s = b1[n] + (b2 ? b2[n] : 0.f);
#pragma unroll
    for (int j = 0; j < 8; ++j) s += P[(long)j * N + n];
    out[n] = s;
}

// ---------------- Mt[n][k] = bf16(MTf[n][k] + p2w[k][n]) ----------------
__global__ __launch_bounds__(256) void k_madd(const float* __restrict__ MTf, const float* __restrict__ p2w,
                                              bf16* __restrict__ Mt)
{
    const int n = blockIdx.x;
    for (int k = threadIdx.x; k < 768; k += 256)
        Mt[n * 768 + k] = (bf16)(MTf[n * 768 + k] + p2w[(long)k * 768 + n]);
}

// ---------------- fused attention per patch ----------------
__global__ __launch_bounds__(256) void k_attn(
    const bf16* __restrict__ q, const bf16* __restrict__ k, const bf16* __restrict__ v,
    float* __restrict__ attn)
{
    const int n = blockIdx.x;
    __shared__ bf16 QT[64 * 72];
    __shared__ bf16 KT[64 * 72];
    __shared__ float S[64 * 66];
    __shared__ bf16 P[64 * 72];
    __shared__ bf16 VT[128 * 72];

    const int tid = threadIdx.x, lane = tid & 63, wave = tid >> 6;
    const int wm = wave >> 1, wn = wave & 1;

    f32x4 accs[2][2];
#pragma unroll
    for (int i = 0; i < 2; ++i)
#pragma unroll
        for (int j = 0; j < 2; ++j) accs[i][j] = (f32x4){0.f, 0.f, 0.f, 0.f};

    for (int kt = 0; kt < 12; ++kt) {
#pragma unroll
        for (int i = 0; i < 2; ++i) {
            int cid = tid + i * 256;
            int r = cid >> 3, seg = cid & 7;
            *(bf16x8*)&QT[r * 72 + seg * 8] = *(const bf16x8*)(q + (long)r * ROWEL + n * 768 + kt * 64 + seg * 8);
            *(bf16x8*)&KT[r * 72 + seg * 8] = *(const bf16x8*)(k + (long)r * ROWEL + n * 768 + kt * 64 + seg * 8);
        }
        __syncthreads();
#pragma unroll
        for (int ks = 0; ks < 2; ++ks) {
            bf16x8 qa[2], kb[2];
#pragma unroll
            for (int i = 0; i < 2; ++i)
                qa[i] = *(const bf16x8*)&QT[(wm * 32 + i * 16 + (lane & 15)) * 72 + ks * 32 + (lane >> 4) * 8];
#pragma unroll
            for (int j = 0; j < 2; ++j)
                kb[j] = *(const bf16x8*)&KT[(wn * 32 + j * 16 + (lane & 15)) * 72 + ks * 32 + (lane >> 4) * 8];
#pragma unroll
            for (int i = 0; i < 2; ++i)
#pragma unroll
                for (int j = 0; j < 2; ++j)
                    accs[i][j] = __builtin_amdgcn_mfma_f32_16x16x32_bf16(qa[i], kb[j], accs[i][j], 0, 0, 0);
        }
        __syncthreads();
    }
    const float sc = 0.03608439182435161f;
#pragma unroll
    for (int i = 0; i < 2; ++i)
#pragma unroll
        for (int j = 0; j < 2; ++j)
#pragma unroll
            for (int r = 0; r < 4; ++r)
                S[(wm * 32 + i * 16 + (lane >> 4) * 4 + r) * 66 + wn * 32 + j * 16 + (lane & 15)] = accs[i][j][r] * sc;
    __syncthreads();

    {
        int r = tid >> 2, l4 = tid & 3;
        float m = -1e30f;
        for (int c = l4; c < 64; c += 4) m = fmaxf(m, S[r * 66 + c]);
        m = fmaxf(m, __shfl_xor(m, 1));
        m = fmaxf(m, __shfl_xor(m, 2));
        float s = 0.f;
        for (int c = l4; c < 64; c += 4) { float e = __expf(S[r * 66 + c] - m); S[r * 66 + c] = e; s += e; }
        s += __shfl_xor(s, 1);
        s += __shfl_xor(s, 2);
        float inv = 1.f / s;
        for (int c = l4; c < 64; c += 4) P[r * 72 + c] = (bf16)(S[r * 66 + c] * inv);
    }
    __syncthreads();

    for (int dc = 0; dc < 6; ++dc) {
#pragma unroll
        for (int i = 0; i < 4; ++i) {
            int cid = tid + i * 256;
            int c = cid >> 4, seg = cid & 15;
            bf16x8 vv = *(const bf16x8*)(v + (long)c * ROWEL + n * 768 + dc * 128 + seg * 8);
#pragma unroll
            for (int e = 0; e < 8; ++e)
                VT[(seg * 8 + e) * 72 + c] = vv[e];
        }
        __syncthreads();
        f32x4 acco[2][4];
#pragma unroll
        for (int i = 0; i < 2; ++i)
#pragma unroll
            for (int j = 0; j < 4; ++j) acco[i][j] = (f32x4){0.f, 0.f, 0.f, 0.f};
#pragma unroll
        for (int ks = 0; ks < 2; ++ks) {
            bf16x8 pa[2], vb[4];
#pragma unroll
            for (int i = 0; i < 2; ++i)
                pa[i] = *(const bf16x8*)&P[(wm * 32 + i * 16 + (lane & 15)) * 72 + ks * 32 + (lane >> 4) * 8];
#pragma unroll
            for (int j = 0; j < 4; ++j)
                vb[j] = *(const bf16x8*)&VT[(wn * 64 + j * 16 + (lane & 15)) * 72 + ks * 32 + (lane >> 4) * 8];
#pragma unroll
            for (int i = 0; i < 2; ++i)
#pragma unroll
                for (int j = 0; j < 4; ++j)
                    acco[i][j] = __builtin_amdgcn_mfma_f32_16x16x32_bf16(pa[i], vb[j], acco[i][j], 0, 0, 0);
        }
#pragma unroll
        for (int i = 0; i < 2; ++i)
#pragma unroll
            for (int j = 0; j < 4; ++j)
#pragma unroll
                for (int r = 0; r < 4; ++r) {
                    long b = wm * 32 + i * 16 + (lane >> 4) * 4 + r;
                    int d = dc * 128 + wn * 64 + j * 16 + (lane & 15);
                    attn[b * ROWEL + n * 768 + d] = acco[i][j][r];
                }
        __syncthreads();
    }
}

// ---------------- LayerNorm over last dim (768), in place ----------------
__global__ __launch_bounds__(256) void k_ln(float* __restrict__ a,
                                            const float* __restrict__ g, const float* __restrict__ bb)
{
    const long row = blockIdx.x * 4 + (threadIdx.x >> 6);
    const int lane = threadIdx.x & 63;
    float* p = a + row * 768;
    f32x4 xv[3];
    float s = 0.f;
#pragma unroll
    for (int c = 0; c < 3; ++c) {
        xv[c] = *(const f32x4*)(p + c * 256 + lane * 4);
        s += xv[c][0] + xv[c][1] + xv[c][2] + xv[c][3];
    }
#pragma unroll
    for (int o = 1; o < 64; o <<= 1) s += __shfl_xor(s, o);
    const float mu = s * (1.f / 768.f);
    float vs = 0.f;
#pragma unroll
    for (int c = 0; c < 3; ++c)
#pragma unroll
        for (int e = 0; e < 4; ++e) { float d = xv[c][e] - mu; vs += d * d; }
#pragma unroll
    for (int o = 1; o < 64; o <<= 1) vs += __shfl_xor(vs, o);
    const float rstd = rsqrtf(vs * (1.f / 768.f) + 1e-5f);
#pragma unroll
    for (int c = 0; c < 3; ++c)
#pragma unroll
        for (int e = 0; e < 4; ++e) {
            int col = c * 256 + lane * 4 + e;
            p[col] = (xv[c][e] - mu) * rstd * g[col] + bb[col];
        }
}

// ---------------- row softmax over 768, in place ----------------
__global__ __launch_bounds__(256) void k_softmax(float* __restrict__ o)
{
    const long row = blockIdx.x * 4 + (threadIdx.x >> 6);
    const int lane = threadIdx.x & 63;
    float* p = o + row * 768;
    f32x4 xv[3];
    float m = -1e30f;
#pragma unroll
    for (int c = 0; c < 3; ++c) {
        xv[c] = *(const f32x4*)(p + c * 256 + lane * 4);
        m = fmaxf(m, fmaxf(fmaxf(xv[c][0], xv[c][1]), fmaxf(xv[c][2], xv[c][3])));
    }
#pragma unroll
    for (int o2 = 1; o2 < 64; o2 <<= 1) m = fmaxf(m, __shfl_xor(m, o2));
    float s = 0.f;
#pragma unroll
    for (int c = 0; c < 3; ++c)
#pragma unroll
        for (int e = 0; e < 4; ++e) { float ev = __expf(xv[c][e] - m); xv[c][e] = ev; s += ev; }
#pragma unroll
    for (int o2 = 1; o2 < 64; o2 <<= 1) s += __shfl_xor(s, o2);
    const float inv = 1.f / s;
#pragma unroll
    for (int c = 0; c < 3; ++c)
        *(f32x4*)(p + c * 256 + lane * 4) = xv[c] * inv;
}

extern "C" void kernel_launch(void* const* d_in, const int* in_sizes, int n_in,
                              void* d_out, int out_size, void* d_ws, size_t ws_size,
                              hipStream_t stream)
{
    const float* x   = (const float*)d_in[0];
    const float* Wq  = (const float*)d_in[1];
    const float* bq  = (const float*)d_in[2];
    const float* Wk  = (const float*)d_in[3];
    const float* bk  = (const float*)d_in[4];
    const float* Wv  = (const float*)d_in[5];
    const float* bv  = (const float*)d_in[6];
    const float* lng = (const float*)d_in[7];
    const float* lnb = (const float*)d_in[8];
    const float* p1w = (const float*)d_in[9];
    const float* p1b = (const float*)d_in[10];
    const float* w0  = (const float*)d_in[11];
    const float* b0  = (const float*)d_in[12];
    const float* w1  = (const float*)d_in[13];
    const float* b1  = (const float*)d_in[14];
    const float* w2  = (const float*)d_in[15];
    const float* b2  = (const float*)d_in[16];
    const float* w3  = (const float*)d_in[17];
    const float* b3  = (const float*)d_in[18];
    const float* w4  = (const float*)d_in[19];
    const float* b4  = (const float*)d_in[20];
    const float* p2w = (const float*)d_in[21];
    const float* p2b = (const float*)d_in[22];
    float* out = (float*)d_out;

    char* wsbase = (char*)d_ws;
    size_t off = 0;
    auto alloc = [&](size_t bytes) { char* p = wsbase + off; off += (bytes + 255) & ~(size_t)255; return p; };
    bf16*  flat = (bf16*)alloc(4096L * 768 * 2);
    bf16*  qb   = (bf16*)alloc(4096L * 768 * 2);
    bf16*  kb   = (bf16*)alloc(4096L * 768 * 2);
    bf16*  vb2  = (bf16*)alloc(4096L * 768 * 2);
    float* attn = (float*)alloc(4096L * 768 * 4);
    bf16*  att  = (bf16*)alloc(4096L * 768 * 2);
    bf16*  p1t  = (bf16*)alloc(768L * 768 * 2);
    bf16*  w0c  = (bf16*)alloc(768L * 3072 * 2);
    bf16*  w1c  = (bf16*)alloc(3072L * 3072 * 2);
    bf16*  w2c  = (bf16*)alloc(3072L * 3072 * 2);
    bf16*  w3c  = (bf16*)alloc(3072L * 3072 * 2);
    bf16*  w4t  = (bf16*)alloc(768L * 3072 * 2);
    bf16*  M1   = (bf16*)alloc(768L * 3072 * 2);
    bf16*  M2   = (bf16*)alloc(768L * 3072 * 2);
    float* MTf  = (float*)alloc(768L * 768 * 4);
    bf16*  Mt   = (bf16*)alloc(768L * 768 * 2);
    float* vP   = (float*)alloc(8L * 3072 * 4);
    float* c1   = (float*)alloc(3072 * 4);
    float* c2   = (float*)alloc(3072 * 4);
    float* c3   = (float*)alloc(3072 * 4);
    float* c4   = (float*)alloc(768 * 4);
    if (off > ws_size) return;

    // ---- activation path ----
    k_patchify<<<dim3(64, 64), 256, 0, stream>>>(x, flat);
    k_qkv<<<dim3(12, 64), 256, 0, stream>>>(flat, Wq, bq, qb);
    k_qkv<<<dim3(12, 64), 256, 0, stream>>>(flat, Wk, bk, kb);
    k_qkv<<<dim3(12, 64), 256, 0, stream>>>(flat, Wv, bv, vb2);
    k_attn<<<64, 256, 0, stream>>>(qb, kb, vb2, attn);
    k_ln<<<1024, 256, 0, stream>>>(attn, lng, lnb);
    k_cvt_t<<<dim3(12, 12), 256, 0, stream>>>(p1w, p1t, 768, 768);
    // att = ln + flat @ p1_w + p1_b -> bf16
    k_gemm_bt<64, 128><<<dim3(64, 6), 256, 0, stream>>>(flat, 768, p1t, 768, 768, p1b, attn, att, nullptr, 768);

    // ---- weight collapse: Mt = (w0 w1 w2 w3 w4)^T, computed as w4^T w3^T w2^T w1^T w0^T ----
    k_cvt_t<<<dim3(48, 12), 256, 0, stream>>>(w4, w4t, 3072, 768);
    k_cast<<<4608, 256, 0, stream>>>(w1, w1c, 3072L * 3072);
    k_cast<<<4608, 256, 0, stream>>>(w2, w2c, 3072L * 3072);
    k_cast<<<4608, 256, 0, stream>>>(w3, w3c, 3072L * 3072);
    k_cast<<<1152, 256, 0, stream>>>(w0, w0c, 768L * 3072);

    k_gemm_bt<64, 128><<<dim3(12, 24), 256, 0, stream>>>(w4t, 3072, w3c, 3072, 3072, nullptr, nullptr, M1, nullptr, 3072);
    k_gemm_bt<64, 128><<<dim3(12, 24), 256, 0, stream>>>(M1, 3072, w2c, 3072, 3072, nullptr, nullptr, M2, nullptr, 3072);
    k_gemm_bt<64, 128><<<dim3(12, 24), 256, 0, stream>>>(M2, 3072, w1c, 3072, 3072, nullptr, nullptr, M1, nullptr, 3072);
    k_gemm_bt<64, 64><<<dim3(12, 12), 256, 0, stream>>>(M1, 3072, w0c, 3072, 3072, nullptr, nullptr, nullptr, MTf, 768);
    k_madd<<<768, 256, 0, stream>>>(MTf, p2w, Mt);

    // ---- bias chain (exact fp32): c = ((((b0@w1+b1)@w2+b2)@w3+b3)@w4+b4)+p2b ----
    k_vm<<<dim3(48, 8), 256, 0, stream>>>(b0, w1, 3072, 3072, vP);
    k_vred<<<12, 256, 0, stream>>>(vP, b1, nullptr, 3072, c1);
    k_vm<<<dim3(48, 8), 256, 0, stream>>>(c1, w2, 3072, 3072, vP);
    k_vred<<<12, 256, 0, stream>>>(vP, b2, nullptr, 3072, c2);
    k_vm<<<dim3(48, 8), 256, 0, stream>>>(c2, w3, 3072, 3072, vP);
    k_vred<<<12, 256, 0, stream>>>(vP, b3, nullptr, 3072, c3);
    k_vm<<<dim3(12, 8), 256, 0, stream>>>(c3, w4, 3072, 768, vP);
    k_vred<<<3, 256, 0, stream>>>(vP, b4, p2b, 768, c4);

    // ---- out = att @ (M + p2w) + c ----
    k_gemm_bt<64, 128><<<dim3(64, 6), 256, 0, stream>>>(att, 768, Mt, 768, 768, c4, nullptr, nullptr, out, 768);
    k_softmax<<<1024, 256, 0, stream>>>(out);
}